// Round 5
// baseline (440.468 us; speedup 1.0000x reference)
//
#include <hip/hip_runtime.h>
#include <stdint.h>

typedef int v4i   __attribute__((ext_vector_type(4)));
typedef int v16i  __attribute__((ext_vector_type(16)));

#define B_    128
#define C_    64
#define H_    56
#define W_    56
#define HW_   3136
#define NELEM (B_*C_*HW_)          // 25,690,112

// int8 tensors: g-split layout [n][y][g=ci/16][x][16] -> conv fragment loads are
// lane-consecutive 16B chunks (fully coalesced global reads, no LDS needed).
#define OFF_K0   0
#define OFF_K1   ((size_t)NELEM)
#define OFF_WB   ((size_t)2*NELEM)                  // int8 [2][g=4][s=9][co=64][16]
#define OFF_PAR  (OFF_WB + 2*4*9*64*16)             // float qw[128] qb[128] aqlut[1024] | double Kd[128] | float xqlut[15]
#define OFF_MAX  (OFF_PAR + 6208)                   // uint32 absmax bits

// ---------------------------------------------------------------- absmax(x)
__global__ void k_absmax(const float* __restrict__ x, unsigned* __restrict__ maxbits) {
    __shared__ float smax[4];
    const int n4 = NELEM / 4;
    const int stride = gridDim.x * blockDim.x;
    int i = blockIdx.x * blockDim.x + threadIdx.x;
    float ma = 0.f, mb = 0.f;
    for (; i + stride < n4; i += 2 * stride) {       // 2 streams for MLP
        float4 va = ((const float4*)x)[i];
        float4 vb = ((const float4*)x)[i + stride];
        ma = fmaxf(ma, fmaxf(fmaxf(fabsf(va.x), fabsf(va.y)), fmaxf(fabsf(va.z), fabsf(va.w))));
        mb = fmaxf(mb, fmaxf(fmaxf(fabsf(vb.x), fabsf(vb.y)), fmaxf(fabsf(vb.z), fabsf(vb.w))));
    }
    if (i < n4) {
        float4 va = ((const float4*)x)[i];
        ma = fmaxf(ma, fmaxf(fmaxf(fabsf(va.x), fabsf(va.y)), fmaxf(fabsf(va.z), fabsf(va.w))));
    }
    float m = fmaxf(ma, mb);
    for (int off = 32; off; off >>= 1) m = fmaxf(m, __shfl_down(m, off, 64));
    if ((threadIdx.x & 63) == 0) smax[threadIdx.x >> 6] = m;
    __syncthreads();
    if (threadIdx.x == 0) {
        float mm = fmaxf(fmaxf(smax[0], smax[1]), fmaxf(smax[2], smax[3]));
        atomicMax(maxbits, __float_as_uint(mm));   // nonneg: uint order == float order
    }
}

// ------------------------------------- quantize x -> int8 k, g-split layout
__global__ void k_quant(const float* __restrict__ x, const unsigned* __restrict__ maxbits,
                        int8_t* __restrict__ k8) {
    __shared__ __align__(16) int8_t tile[W_ * C_];   // [x][c]
    const int n = blockIdx.x / H_;
    const int y = blockIdx.x % H_;
    const float T = fminf(fmaxf(__uint_as_float(*maxbits), 1e-10f), 255.0f);
    for (int i = threadIdx.x; i < C_ * 14; i += blockDim.x) {
        int c = i / 14, j = i % 14;
        float4 v = *(const float4*)(x + ((size_t)(n * C_ + c)) * HW_ + y * W_ + j * 4);
        float vv[4] = {v.x, v.y, v.z, v.w};
#pragma unroll
        for (int q = 0; q < 4; q++) {
            float t = fminf(fmaxf(vv[q], -T), T);
            float u = __fdiv_rn(t, T);
            int k = (int)rintf(__fmul_rn(u, 7.0f));
            tile[(j * 4 + q) * C_ + c] = (int8_t)k;
        }
    }
    __syncthreads();
    if (threadIdx.x < 224) {
        int g = threadIdx.x / 56, xx = threadIdx.x % 56;
        *(int4*)(k8 + ((((size_t)(n * 56 + y)) * 4 + g) * 56 + xx) * 16) =
            *(const int4*)(tile + xx * 64 + g * 16);
    }
}

// --------------------------- weight binarization, numpy-pairwise-faithful f32
__device__ __forceinline__ float pw_reduce64(float r) {
    r = __fadd_rn(r, __shfl_xor(r, 1, 64));
    r = __fadd_rn(r, __shfl_xor(r, 2, 64));
    r = __fadd_rn(r, __shfl_xor(r, 4, 64));
    r = __fadd_rn(r, __shfl_xor(r, 8, 64));
    r = __fadd_rn(r, __shfl_xor(r, 16, 64));
    r = __fadd_rn(r, __shfl_xor(r, 32, 64));
    return r;
}

__global__ void k_prepw(const float* __restrict__ w1, const float* __restrict__ w2,
                        int8_t* __restrict__ wb, float* __restrict__ par) {
    const int layer = blockIdx.x >> 6;
    const int co    = blockIdx.x & 63;
    const float* w = (layer ? w2 : w1) + (size_t)co * 576;
    const int lane = threadIdx.x;
    const int base = (lane >> 3) * 72 + (lane & 7);

    float v[9];
#pragma unroll
    for (int i = 0; i < 9; i++) v[i] = w[base + 8 * i];

    float s = v[0];
#pragma unroll
    for (int i = 1; i < 9; i++) s = __fadd_rn(s, v[i]);
    const float mean = __fdiv_rn(pw_reduce64(s), 576.0f);

    float d0 = __fsub_rn(v[0], mean);
    float sq = __fmul_rn(d0, d0);
#pragma unroll
    for (int i = 1; i < 9; i++) {
        float d = __fsub_rn(v[i], mean);
        sq = __fadd_rn(sq, __fmul_rn(d, d));
    }
    const float sig = __fsqrt_rn(__fdiv_rn(pw_reduce64(sq), 575.0f));

    float sa = fabsf(__fdiv_rn(__fsub_rn(v[0], mean), sig));
#pragma unroll
    for (int i = 1; i < 9; i++)
        sa = __fadd_rn(sa, fabsf(__fdiv_rn(__fsub_rn(v[i], mean), sig)));
    const float ma = __fdiv_rn(pw_reduce64(sa), 576.0f);
    const float p  = rintf(log2f(ma));
    if (lane == 0)
        ((double*)(par + 1280))[layer * 64 + co] = exp2((double)p) * (341.0 / 1344.0);

#pragma unroll
    for (int i = 0; i < 9; i++) {
        int ig = base + 8 * i;
        float d = __fsub_rn(v[i], mean);
        int8_t sg = (d > 0.0f) ? (int8_t)1 : ((d < 0.0f) ? (int8_t)-1 : (int8_t)0);
        int ci = ig / 9, t = ig % 9;
        wb[((((size_t)layer * 4 + (ci >> 4)) * 9 + t) * 64 + co) * 16 + (ci & 15)] = sg;
    }
}

// -------------------------------- BN affine + LUTs
__global__ void k_prepbn(const float* g1, const float* bb1, const float* mm1, const float* vv1,
                         const float* g2, const float* bb2, const float* mm2, const float* vv2,
                         float* __restrict__ par) {
    const int tid = threadIdx.x;
    if (tid < 128) {
        const int layer = tid >> 6;
        const int c = tid & 63;
        const float* g  = layer ? g2  : g1;
        const float* be = layer ? bb2 : bb1;
        const float* mu = layer ? mm2 : mm1;
        const float* va = layer ? vv2 : vv1;
        const float stdv = __fsqrt_rn(__fadd_rn(va[c], 1e-5f));
        const float w = __fdiv_rn(g[c], stdv);
        const float b = __fsub_rn(be[c], __fmul_rn(w, mu[c]));
        float aw = fabsf(w), ab = fabsf(b);
        for (int off = 32; off; off >>= 1) {
            aw = fmaxf(aw, __shfl_xor(aw, off, 64));
            ab = fmaxf(ab, __shfl_xor(ab, off, 64));
        }
        const float Tw = fminf(fmaxf(aw, 1e-10f), 255.0f);
        const float Tb = fminf(fmaxf(ab, 1e-10f), 255.0f);
        {
            float vq = __fdiv_rn(fminf(fmaxf(w, -Tw), Tw), Tw);
            float r  = rintf(__fmul_rn(vq, 7.0f));
            float qf = __fadd_rn(vq, __fsub_rn(__fdiv_rn(r, 7.0f), vq));
            par[layer * 64 + c] = __fmul_rn(qf, Tw);
        }
        {
            float vq = __fdiv_rn(fminf(fmaxf(b, -Tb), Tb), Tb);
            float r  = rintf(__fmul_rn(vq, 4095.0f));
            float qf = __fadd_rn(vq, __fsub_rn(__fdiv_rn(r, 4095.0f), vq));
            par[128 + layer * 64 + c] = __fmul_rn(qf, Tb);
        }
    }
    // aq LUT: aq(rr) = fmul(fdiv(rr,1023),576)  (== ref chain; y1==q1 by Sterbenz)
    for (int i = tid; i < 1024; i += blockDim.x)
        par[256 + i] = __fmul_rn(__fdiv_rn((float)i, 1023.0f), 576.0f);
    // xq LUT: xq(k) = fdiv(k,7), k in [-7,7]
    if (tid < 15) par[1536 + tid] = __fdiv_rn((float)(tid - 7), 7.0f);
}

// ------------------------------------------------ fused conv + BN + residual
// grid: B*14 blocks (n, 4 rows) -> M=224, N=64. NO LDS, NO barriers.
// All fragments read directly from global (lane-consecutive 16B, L1/L2-hot).
// conv1: acc[T][t] = mfma(xf,wf)  -> C col(lane)=co  (good for int8 g-split store)
// conv2: acc[t][T] = mfma(wf,xf)  -> C col(lane)=m   (coalesced f32 NCHW store)
template <int LAYER>
__global__ __launch_bounds__(256) void k_conv(const int8_t* __restrict__ kin,
                                              const int8_t* __restrict__ wb,
                                              const float* __restrict__ par,
                                              int8_t* __restrict__ kout,
                                              float* __restrict__ fout) {
    const int n  = blockIdx.x / 14;
    const int y0 = (blockIdx.x % 14) * 4;
    const int tid = threadIdx.x;
    const int wv = tid >> 6, lane = tid & 63;
    const int ml = lane & 31, khalf = lane >> 5;
    const int wvbase = wv * 64;

    const int8_t* kn   = kin + (size_t)n * (HW_ * 64);      // n-slice of g-split tensor
    const int8_t* wsrc = wb + (size_t)(LAYER - 1) * 36864;

    int rmT[2], cmT[2];
#pragma unroll
    for (int T = 0; T < 2; T++) {
        int m = wvbase + T * 32 + ml;
        if (m > 223) m = 223;
        int q = (m * 586) >> 15;                 // m/56 for m<224
        rmT[T] = q; cmT[T] = m - q * 56;
    }

    v16i acc[2][2];
#pragma unroll
    for (int a = 0; a < 2; a++)
#pragma unroll
        for (int b = 0; b < 2; b++)
#pragma unroll
            for (int i = 0; i < 16; i++) acc[a][b][i] = 0;

#pragma unroll
    for (int s = 0; s < 9; s++) {
        const int ky = s / 3, kx = s % 3;
#pragma unroll
        for (int kb = 0; kb < 2; kb++) {
            const int g = kb * 2 + khalf;
            v4i xf[2], wf[2];
#pragma unroll
            for (int T = 0; T < 2; T++) {
                const int y  = y0 + rmT[T] + ky - 1;
                const int xg = cmT[T] + kx - 1;
                v4i v = {0, 0, 0, 0};
                if ((unsigned)y < 56u && (unsigned)xg < 56u)
                    v = *(const v4i*)(kn + (((size_t)y * 4 + g) * 56 + xg) * 16);
                xf[T] = v;
            }
#pragma unroll
            for (int t = 0; t < 2; t++)
                wf[t] = *(const v4i*)(wsrc + ((g * 9 + s) * 64 + ml + 32 * t) * 16);
            if (LAYER == 1) {
                acc[0][0] = __builtin_amdgcn_mfma_i32_32x32x32_i8(xf[0], wf[0], acc[0][0], 0, 0, 0);
                acc[0][1] = __builtin_amdgcn_mfma_i32_32x32x32_i8(xf[0], wf[1], acc[0][1], 0, 0, 0);
                acc[1][0] = __builtin_amdgcn_mfma_i32_32x32x32_i8(xf[1], wf[0], acc[1][0], 0, 0, 0);
                acc[1][1] = __builtin_amdgcn_mfma_i32_32x32x32_i8(xf[1], wf[1], acc[1][1], 0, 0, 0);
            } else {
                acc[0][0] = __builtin_amdgcn_mfma_i32_32x32x32_i8(wf[0], xf[0], acc[0][0], 0, 0, 0);
                acc[0][1] = __builtin_amdgcn_mfma_i32_32x32x32_i8(wf[0], xf[1], acc[0][1], 0, 0, 0);
                acc[1][0] = __builtin_amdgcn_mfma_i32_32x32x32_i8(wf[1], xf[0], acc[1][0], 0, 0, 0);
                acc[1][1] = __builtin_amdgcn_mfma_i32_32x32x32_i8(wf[1], xf[1], acc[1][1], 0, 0, 0);
            }
        }
    }

    const float* qw  = par + (LAYER - 1) * 64;
    const float* qb  = par + 128 + (LAYER - 1) * 64;
    const float* aql = par + 256;
    const float* xql = par + 1536;
    const double* Kd = (const double*)(par + 1280) + (LAYER - 1) * 64;

    if (LAYER == 1) {
        // C: col(lane)=co=ml+32t, row=mrow
#pragma unroll
        for (int t = 0; t < 2; t++) {
            const int co = ml + 32 * t;
            const float qwf = qw[co], qbf = qb[co];
            const double Kc = Kd[co];
#pragma unroll
            for (int T = 0; T < 2; T++) {
#pragma unroll
                for (int r = 0; r < 16; r++) {
                    const int mrow = wvbase + T * 32 + 4 * khalf + (r & 3) + 8 * (r >> 2);
                    if (mrow > 223) continue;
                    const int S = acc[T][t][r];
                    const int rri = (int)rint((double)S * Kc);
                    const int idx = rri < 0 ? -rri : rri;
                    float aqa = (idx <= 1023) ? aql[idx]
                              : __fmul_rn(__fdiv_rn((float)idx, 1023.0f), 576.0f);
                    const float aq = rri < 0 ? -aqa : aqa;
                    const int rloc = (mrow * 586) >> 15;
                    const int cloc = mrow - rloc * 56;
                    const int kc = (int)kn[((((size_t)(y0 + rloc)) * 4 + (co >> 4)) * 56 + cloc) * 16 + (co & 15)];
                    const float xq = xql[kc + 7];
                    float val = __fadd_rn(__fadd_rn(__fmul_rn(aq, qwf), qbf), xq);
                    val = fminf(fmaxf(val, -1.0f), 1.0f);
                    const int k2 = (int)rintf(__fmul_rn(val, 7.0f));   // T1 == 1.0
                    kout[((((size_t)(n * 56 + y0 + rloc)) * 4 + (co >> 4)) * 56 + cloc) * 16 + (co & 15)]
                        = (int8_t)k2;
                }
            }
        }
    } else {
        // C: col(lane)=m (within T tile), row=co=(r&3)+8*(r>>2)+4*khalf+32t
        float* fn = fout + (size_t)n * 64 * HW_;
#pragma unroll
        for (int t = 0; t < 2; t++) {
#pragma unroll
            for (int r = 0; r < 16; r++) {
                const int co = (r & 3) + 8 * (r >> 2) + 4 * khalf + 32 * t;
                const float qwf = qw[co], qbf = qb[co];
                const double Kc = Kd[co];
#pragma unroll
                for (int T = 0; T < 2; T++) {
                    const int m = wvbase + T * 32 + ml;
                    if (m > 223) continue;
                    const int S = acc[t][T][r];
                    const int rri = (int)rint((double)S * Kc);
                    const int idx = rri < 0 ? -rri : rri;
                    float aqa = (idx <= 1023) ? aql[idx]
                              : __fmul_rn(__fdiv_rn((float)idx, 1023.0f), 576.0f);
                    const float aq = rri < 0 ? -aqa : aqa;
                    const int kc = (int)kn[((((size_t)(y0 + rmT[T])) * 4 + (co >> 4)) * 56 + cmT[T]) * 16 + (co & 15)];
                    const float xq = xql[kc + 7];
                    float val = __fadd_rn(__fadd_rn(__fmul_rn(aq, qwf), qbf), xq);
                    val = fminf(fmaxf(val, -1.0f), 1.0f);
                    fn[(size_t)co * HW_ + (size_t)(y0 + rmT[T]) * 56 + cmT[T]] = val;
                }
            }
        }
    }
}

// ----------------------------------------------------------------- launcher
extern "C" void kernel_launch(void* const* d_in, const int* in_sizes, int n_in,
                              void* d_out, int out_size, void* d_ws, size_t ws_size,
                              hipStream_t stream) {
    const float* x  = (const float*)d_in[0];
    const float* w1 = (const float*)d_in[1];
    const float* w2 = (const float*)d_in[2];
    const float* g1 = (const float*)d_in[3];
    const float* b1 = (const float*)d_in[4];
    const float* m1 = (const float*)d_in[5];
    const float* v1 = (const float*)d_in[6];
    const float* g2 = (const float*)d_in[7];
    const float* b2 = (const float*)d_in[8];
    const float* m2 = (const float*)d_in[9];
    const float* v2 = (const float*)d_in[10];

    char* ws = (char*)d_ws;
    int8_t*  k0  = (int8_t*)(ws + OFF_K0);
    int8_t*  k1  = (int8_t*)(ws + OFF_K1);
    int8_t*  wbp = (int8_t*)(ws + OFF_WB);
    float*   par = (float*)(ws + OFF_PAR);
    unsigned* mx = (unsigned*)(ws + OFF_MAX);

    hipMemsetAsync(mx, 0, 4, stream);
    k_absmax<<<1024, 256, 0, stream>>>(x, mx);
    k_quant<<<B_ * H_, 256, 0, stream>>>(x, mx, k0);
    k_prepw<<<128, 64, 0, stream>>>(w1, w2, wbp, par);
    k_prepbn<<<1, 256, 0, stream>>>(g1, b1, m1, v1, g2, b2, m2, v2, par);
    k_conv<1><<<B_ * 14, 256, 0, stream>>>(k0, wbp, par, k1, nullptr);
    k_conv<2><<<B_ * 14, 256, 0, stream>>>(k1, wbp, par, nullptr, (float*)d_out);
}

// Round 6
// 417.081 us; speedup vs baseline: 1.0561x; 1.0561x over previous
//
#include <hip/hip_runtime.h>
#include <stdint.h>

typedef int v4i   __attribute__((ext_vector_type(4)));
typedef int v16i  __attribute__((ext_vector_type(16)));

#define B_    128
#define C_    64
#define H_    56
#define W_    56
#define HW_   3136
#define NELEM (B_*C_*HW_)          // 25,690,112

// int8 tensors: g-split layout [n][y][g=ci/16][x][16] -> staging loads and LDS
// fragment reads are lane-consecutive 16B chunks (coalesced / conflict-free).
#define OFF_K0   0
#define OFF_K1   ((size_t)NELEM)
#define OFF_WB   ((size_t)2*NELEM)                  // int8 [2][g=4][s=9][co=64][16]
#define OFF_PAR  (OFF_WB + 2*4*9*64*16)             // float qw[128] qb[128] aqlut[1024] | double Kd[128] | float xqlut[15]
#define OFF_MAX  (OFF_PAR + 6208)                   // uint32 absmax bits

// ---------------------------------------------------------------- absmax(x)
__global__ void k_absmax(const float* __restrict__ x, unsigned* __restrict__ maxbits) {
    __shared__ float smax[4];
    const int n4 = NELEM / 4;
    const int stride = gridDim.x * blockDim.x;
    int i = blockIdx.x * blockDim.x + threadIdx.x;
    float ma = 0.f, mb = 0.f;
    for (; i + stride < n4; i += 2 * stride) {
        float4 va = ((const float4*)x)[i];
        float4 vb = ((const float4*)x)[i + stride];
        ma = fmaxf(ma, fmaxf(fmaxf(fabsf(va.x), fabsf(va.y)), fmaxf(fabsf(va.z), fabsf(va.w))));
        mb = fmaxf(mb, fmaxf(fmaxf(fabsf(vb.x), fabsf(vb.y)), fmaxf(fabsf(vb.z), fabsf(vb.w))));
    }
    if (i < n4) {
        float4 va = ((const float4*)x)[i];
        ma = fmaxf(ma, fmaxf(fmaxf(fabsf(va.x), fabsf(va.y)), fmaxf(fabsf(va.z), fabsf(va.w))));
    }
    float m = fmaxf(ma, mb);
    for (int off = 32; off; off >>= 1) m = fmaxf(m, __shfl_down(m, off, 64));
    if ((threadIdx.x & 63) == 0) smax[threadIdx.x >> 6] = m;
    __syncthreads();
    if (threadIdx.x == 0) {
        float mm = fmaxf(fmaxf(smax[0], smax[1]), fmaxf(smax[2], smax[3]));
        atomicMax(maxbits, __float_as_uint(mm));   // nonneg: uint order == float order
    }
}

// ------------------------------------- quantize x -> int8 k, g-split layout
__global__ void k_quant(const float* __restrict__ x, const unsigned* __restrict__ maxbits,
                        int8_t* __restrict__ k8) {
    __shared__ __align__(16) int8_t tile[W_ * C_];   // [x][c]
    const int n = blockIdx.x / H_;
    const int y = blockIdx.x % H_;
    const float T = fminf(fmaxf(__uint_as_float(*maxbits), 1e-10f), 255.0f);
    for (int i = threadIdx.x; i < C_ * 14; i += blockDim.x) {
        int c = i / 14, j = i % 14;
        float4 v = *(const float4*)(x + ((size_t)(n * C_ + c)) * HW_ + y * W_ + j * 4);
        float vv[4] = {v.x, v.y, v.z, v.w};
#pragma unroll
        for (int q = 0; q < 4; q++) {
            float t = fminf(fmaxf(vv[q], -T), T);
            float u = __fdiv_rn(t, T);
            int k = (int)rintf(__fmul_rn(u, 7.0f));
            tile[(j * 4 + q) * C_ + c] = (int8_t)k;
        }
    }
    __syncthreads();
    if (threadIdx.x < 224) {
        int g = threadIdx.x / 56, xx = threadIdx.x % 56;
        *(int4*)(k8 + ((((size_t)(n * 56 + y)) * 4 + g) * 56 + xx) * 16) =
            *(const int4*)(tile + xx * 64 + g * 16);
    }
}

// --------------------------- weight binarization, numpy-pairwise-faithful f32
__device__ __forceinline__ float pw_reduce64(float r) {
    r = __fadd_rn(r, __shfl_xor(r, 1, 64));
    r = __fadd_rn(r, __shfl_xor(r, 2, 64));
    r = __fadd_rn(r, __shfl_xor(r, 4, 64));
    r = __fadd_rn(r, __shfl_xor(r, 8, 64));
    r = __fadd_rn(r, __shfl_xor(r, 16, 64));
    r = __fadd_rn(r, __shfl_xor(r, 32, 64));
    return r;
}

__global__ void k_prepw(const float* __restrict__ w1, const float* __restrict__ w2,
                        int8_t* __restrict__ wb, float* __restrict__ par) {
    const int layer = blockIdx.x >> 6;
    const int co    = blockIdx.x & 63;
    const float* w = (layer ? w2 : w1) + (size_t)co * 576;
    const int lane = threadIdx.x;
    const int base = (lane >> 3) * 72 + (lane & 7);

    float v[9];
#pragma unroll
    for (int i = 0; i < 9; i++) v[i] = w[base + 8 * i];

    float s = v[0];
#pragma unroll
    for (int i = 1; i < 9; i++) s = __fadd_rn(s, v[i]);
    const float mean = __fdiv_rn(pw_reduce64(s), 576.0f);

    float d0 = __fsub_rn(v[0], mean);
    float sq = __fmul_rn(d0, d0);
#pragma unroll
    for (int i = 1; i < 9; i++) {
        float d = __fsub_rn(v[i], mean);
        sq = __fadd_rn(sq, __fmul_rn(d, d));
    }
    const float sig = __fsqrt_rn(__fdiv_rn(pw_reduce64(sq), 575.0f));

    float sa = fabsf(__fdiv_rn(__fsub_rn(v[0], mean), sig));
#pragma unroll
    for (int i = 1; i < 9; i++)
        sa = __fadd_rn(sa, fabsf(__fdiv_rn(__fsub_rn(v[i], mean), sig)));
    const float ma = __fdiv_rn(pw_reduce64(sa), 576.0f);
    const float p  = rintf(log2f(ma));
    if (lane == 0)
        ((double*)(par + 1280))[layer * 64 + co] = exp2((double)p) * (341.0 / 1344.0);

#pragma unroll
    for (int i = 0; i < 9; i++) {
        int ig = base + 8 * i;
        float d = __fsub_rn(v[i], mean);
        int8_t sg = (d > 0.0f) ? (int8_t)1 : ((d < 0.0f) ? (int8_t)-1 : (int8_t)0);
        int ci = ig / 9, t = ig % 9;
        wb[((((size_t)layer * 4 + (ci >> 4)) * 9 + t) * 64 + co) * 16 + (ci & 15)] = sg;
    }
}

// -------------------------------- BN affine + LUTs
__global__ void k_prepbn(const float* g1, const float* bb1, const float* mm1, const float* vv1,
                         const float* g2, const float* bb2, const float* mm2, const float* vv2,
                         float* __restrict__ par) {
    const int tid = threadIdx.x;
    if (tid < 128) {
        const int layer = tid >> 6;
        const int c = tid & 63;
        const float* g  = layer ? g2  : g1;
        const float* be = layer ? bb2 : bb1;
        const float* mu = layer ? mm2 : mm1;
        const float* va = layer ? vv2 : vv1;
        const float stdv = __fsqrt_rn(__fadd_rn(va[c], 1e-5f));
        const float w = __fdiv_rn(g[c], stdv);
        const float b = __fsub_rn(be[c], __fmul_rn(w, mu[c]));
        float aw = fabsf(w), ab = fabsf(b);
        for (int off = 32; off; off >>= 1) {
            aw = fmaxf(aw, __shfl_xor(aw, off, 64));
            ab = fmaxf(ab, __shfl_xor(ab, off, 64));
        }
        const float Tw = fminf(fmaxf(aw, 1e-10f), 255.0f);
        const float Tb = fminf(fmaxf(ab, 1e-10f), 255.0f);
        {
            float vq = __fdiv_rn(fminf(fmaxf(w, -Tw), Tw), Tw);
            float r  = rintf(__fmul_rn(vq, 7.0f));
            float qf = __fadd_rn(vq, __fsub_rn(__fdiv_rn(r, 7.0f), vq));
            par[layer * 64 + c] = __fmul_rn(qf, Tw);
        }
        {
            float vq = __fdiv_rn(fminf(fmaxf(b, -Tb), Tb), Tb);
            float r  = rintf(__fmul_rn(vq, 4095.0f));
            float qf = __fadd_rn(vq, __fsub_rn(__fdiv_rn(r, 4095.0f), vq));
            par[128 + layer * 64 + c] = __fmul_rn(qf, Tb);
        }
    }
    for (int i = tid; i < 1024; i += blockDim.x)
        par[256 + i] = __fmul_rn(__fdiv_rn((float)i, 1023.0f), 576.0f);
    if (tid < 15) par[1536 + tid] = __fdiv_rn((float)(tid - 7), 7.0f);
}

// ------------------------------------------------ fused conv + BN + residual
// grid: B*28 blocks (n, 2 rows) -> M=112, N=64; 4 waves, one 32-M-tile each.
// LDS 51712 B (3 blocks/CU): halo [g4][r4][x58][16] + weights [g4][s9][co64][16],
// both read as lane-consecutive b128 (conflict-free). No barriers after stage.
// conv1: mfma(x,w) -> C col=co (int8 g-split direct store)
// conv2: mfma(w,x) -> C col=m  (coalesced f32 NCHW direct store)
template <int LAYER>
__global__ __launch_bounds__(256) void k_conv(const int8_t* __restrict__ kin,
                                              const int8_t* __restrict__ wb,
                                              const float* __restrict__ par,
                                              int8_t* __restrict__ kout,
                                              float* __restrict__ fout) {
    __shared__ __align__(16) int8_t halo[4 * 4 * 58 * 16];   // 14848 B
    __shared__ __align__(16) int8_t wsm[4 * 9 * 64 * 16];    // 36864 B
    const int n  = blockIdx.x / 28;
    const int y0 = (blockIdx.x % 28) * 2;
    const int tid = threadIdx.x;

    for (int u = tid; u < 928; u += 256) {            // halo: g4 x r4 x x58
        int xx = u % 58, gr = u / 58;
        int g = gr >> 2, r = gr & 3;
        int y = y0 - 1 + r, xg = xx - 1;
        int4 val = {0, 0, 0, 0};
        if ((unsigned)y < 56u && (unsigned)xg < 56u)
            val = *(const int4*)(kin + ((((size_t)(n * 56 + y)) * 4 + g) * 56 + xg) * 16);
        *(int4*)(halo + ((g * 4 + r) * 58 + xx) * 16) = val;
    }
    const int8_t* wsrc = wb + (size_t)(LAYER - 1) * 36864;
    for (int u = tid; u < 2304; u += 256)
        *(int4*)(wsm + u * 16) = *(const int4*)(wsrc + u * 16);
    __syncthreads();

    const int wv = tid >> 6, lane = tid & 63;
    const int ml = lane & 31, khalf = lane >> 5;
    const int mbase = wv * 32;

    const int m = mbase + ml;
    const int m_eff = (m < 112) ? m : 111;
    const int rm = m_eff / 56, cm = m_eff % 56;

    v16i acc0, acc1;
#pragma unroll
    for (int i = 0; i < 16; i++) { acc0[i] = 0; acc1[i] = 0; }

#pragma unroll
    for (int s = 0; s < 9; s++) {
        const int ky = s / 3, kx = s % 3;
#pragma unroll
        for (int kb = 0; kb < 2; kb++) {
            const int g = kb * 2 + khalf;
            v4i a  = *(const v4i*)(halo + ((g * 4 + rm + ky) * 58 + cm + kx) * 16);
            v4i b0 = *(const v4i*)(wsm + ((g * 9 + s) * 64 + ml) * 16);
            v4i b1 = *(const v4i*)(wsm + ((g * 9 + s) * 64 + ml + 32) * 16);
            if (LAYER == 1) {
                acc0 = __builtin_amdgcn_mfma_i32_32x32x32_i8(a, b0, acc0, 0, 0, 0);
                acc1 = __builtin_amdgcn_mfma_i32_32x32x32_i8(a, b1, acc1, 0, 0, 0);
            } else {
                acc0 = __builtin_amdgcn_mfma_i32_32x32x32_i8(b0, a, acc0, 0, 0, 0);
                acc1 = __builtin_amdgcn_mfma_i32_32x32x32_i8(b1, a, acc1, 0, 0, 0);
            }
        }
    }

    const float* qw  = par + (LAYER - 1) * 64;
    const float* qb  = par + 128 + (LAYER - 1) * 64;
    const float* aql = par + 256;
    const float* xql = par + 1536;
    const double* Kd = (const double*)(par + 1280) + (LAYER - 1) * 64;

    if (LAYER == 1) {
        // C: col(lane)=co=ml+32t, row=mrow
#pragma unroll
        for (int t = 0; t < 2; t++) {
            const int co = ml + 32 * t;
            const float qwf = qw[co], qbf = qb[co];
            const double Kc = Kd[co];
#pragma unroll
            for (int r = 0; r < 16; r++) {
                const int mrow = mbase + 4 * khalf + (r & 3) + 8 * (r >> 2);
                if (mrow >= 112) continue;
                const int S = t ? acc1[r] : acc0[r];
                const int rri = (int)rint((double)S * Kc);
                const int idx = rri < 0 ? -rri : rri;
                float aqa = (idx <= 1023) ? aql[idx]
                          : __fmul_rn(__fdiv_rn((float)idx, 1023.0f), 576.0f);
                const float aq = rri < 0 ? -aqa : aqa;
                const int rloc = mrow / 56, cloc = mrow % 56;
                const int kc = (int)halo[(((co >> 4) * 4 + rloc + 1) * 58 + cloc + 1) * 16 + (co & 15)];
                const float xq = xql[kc + 7];
                float val = __fadd_rn(__fadd_rn(__fmul_rn(aq, qwf), qbf), xq);
                val = fminf(fmaxf(val, -1.0f), 1.0f);
                const int k2 = (int)rintf(__fmul_rn(val, 7.0f));   // T1 == 1.0
                kout[((((size_t)(n * 56 + y0 + rloc)) * 4 + (co >> 4)) * 56 + cloc) * 16 + (co & 15)]
                    = (int8_t)k2;
            }
        }
    } else {
        // C: col(lane)=m, row=co=(r&3)+8*(r>>2)+4*khalf+32t
        // residual kc: 4 conflict-free b128 (this lane's position, all 4 g), unpack bytes
        int kcw[16];
        {
            const int4* hp = (const int4*)halo;
#pragma unroll
            for (int g = 0; g < 4; g++) {
                int4 chunk = hp[(g * 4 + rm + 1) * 58 + cm + 1];
                kcw[g * 4 + 0] = chunk.x; kcw[g * 4 + 1] = chunk.y;
                kcw[g * 4 + 2] = chunk.z; kcw[g * 4 + 3] = chunk.w;
            }
        }
        float* fn = fout + (size_t)n * 64 * HW_ + (size_t)(y0 + rm) * 56 + cm;
        const bool mok = (m < 112);
#pragma unroll
        for (int t = 0; t < 2; t++) {
#pragma unroll
            for (int r = 0; r < 16; r++) {
                const int co = (r & 3) + 8 * (r >> 2) + 4 * khalf + 32 * t;
                const float qwf = qw[co], qbf = qb[co];
                const double Kc = Kd[co];
                const int S = t ? acc1[r] : acc0[r];
                const int rri = (int)rint((double)S * Kc);
                const int idx = rri < 0 ? -rri : rri;
                float aqa = (idx <= 1023) ? aql[idx]
                          : __fmul_rn(__fdiv_rn((float)idx, 1023.0f), 576.0f);
                const float aq = rri < 0 ? -aqa : aqa;
                const int kc = (int)(int8_t)(kcw[co >> 2] >> ((co & 3) * 8));
                const float xq = xql[kc + 7];
                float val = __fadd_rn(__fadd_rn(__fmul_rn(aq, qwf), qbf), xq);
                val = fminf(fmaxf(val, -1.0f), 1.0f);
                if (mok) fn[(size_t)co * HW_] = val;
            }
        }
    }
}

// ----------------------------------------------------------------- launcher
extern "C" void kernel_launch(void* const* d_in, const int* in_sizes, int n_in,
                              void* d_out, int out_size, void* d_ws, size_t ws_size,
                              hipStream_t stream) {
    const float* x  = (const float*)d_in[0];
    const float* w1 = (const float*)d_in[1];
    const float* w2 = (const float*)d_in[2];
    const float* g1 = (const float*)d_in[3];
    const float* b1 = (const float*)d_in[4];
    const float* m1 = (const float*)d_in[5];
    const float* v1 = (const float*)d_in[6];
    const float* g2 = (const float*)d_in[7];
    const float* b2 = (const float*)d_in[8];
    const float* m2 = (const float*)d_in[9];
    const float* v2 = (const float*)d_in[10];

    char* ws = (char*)d_ws;
    int8_t*  k0  = (int8_t*)(ws + OFF_K0);
    int8_t*  k1  = (int8_t*)(ws + OFF_K1);
    int8_t*  wbp = (int8_t*)(ws + OFF_WB);
    float*   par = (float*)(ws + OFF_PAR);
    unsigned* mx = (unsigned*)(ws + OFF_MAX);

    hipMemsetAsync(mx, 0, 4, stream);
    k_absmax<<<2048, 256, 0, stream>>>(x, mx);
    k_quant<<<B_ * H_, 256, 0, stream>>>(x, mx, k0);
    k_prepw<<<128, 64, 0, stream>>>(w1, w2, wbp, par);
    k_prepbn<<<1, 256, 0, stream>>>(g1, b1, m1, v1, g2, b2, m2, v2, par);
    k_conv<1><<<B_ * 28, 256, 0, stream>>>(k0, wbp, par, k1, nullptr);
    k_conv<2><<<B_ * 28, 256, 0, stream>>>(k1, wbp, par, nullptr, (float*)d_out);
}

// Round 7
// 352.619 us; speedup vs baseline: 1.2491x; 1.1828x over previous
//
#include <hip/hip_runtime.h>
#include <stdint.h>

typedef int v4i   __attribute__((ext_vector_type(4)));
typedef int v16i  __attribute__((ext_vector_type(16)));

#define B_    128
#define C_    64
#define H_    56
#define W_    56
#define HW_   3136
#define NELEM (B_*C_*HW_)          // 25,690,112

// int8 tensors: g-split layout [n][y][g=ci/16][x][16] -> staging loads and LDS
// fragment reads are lane-consecutive 16B chunks (coalesced / conflict-free).
#define OFF_K0   0
#define OFF_K1   ((size_t)NELEM)
#define OFF_WB   ((size_t)2*NELEM)                  // int8 [2][g=4][s=9][co=64][16]
#define OFF_PAR  (OFF_WB + 2*4*9*64*16)             // float qw[128] qb[128] sc[128]
#define OFF_MAX  (OFF_PAR + 1536)                   // uint32 absmax bits

// ---------------------------------------------------------------- absmax(x)
__global__ void k_absmax(const float* __restrict__ x, unsigned* __restrict__ maxbits) {
    __shared__ float smax[4];
    const int n4 = NELEM / 4;
    const int stride = gridDim.x * blockDim.x;
    int i = blockIdx.x * blockDim.x + threadIdx.x;
    float ma = 0.f, mb = 0.f;
    for (; i + stride < n4; i += 2 * stride) {
        float4 va = ((const float4*)x)[i];
        float4 vb = ((const float4*)x)[i + stride];
        ma = fmaxf(ma, fmaxf(fmaxf(fabsf(va.x), fabsf(va.y)), fmaxf(fabsf(va.z), fabsf(va.w))));
        mb = fmaxf(mb, fmaxf(fmaxf(fabsf(vb.x), fabsf(vb.y)), fmaxf(fabsf(vb.z), fabsf(vb.w))));
    }
    if (i < n4) {
        float4 va = ((const float4*)x)[i];
        ma = fmaxf(ma, fmaxf(fmaxf(fabsf(va.x), fabsf(va.y)), fmaxf(fabsf(va.z), fabsf(va.w))));
    }
    float m = fmaxf(ma, mb);
    for (int off = 32; off; off >>= 1) m = fmaxf(m, __shfl_down(m, off, 64));
    if ((threadIdx.x & 63) == 0) smax[threadIdx.x >> 6] = m;
    __syncthreads();
    if (threadIdx.x == 0) {
        float mm = fmaxf(fmaxf(smax[0], smax[1]), fmaxf(smax[2], smax[3]));
        atomicMax(maxbits, __float_as_uint(mm));   // nonneg: uint order == float order
    }
}

// ------------------------------------- quantize x -> int8 k, g-split layout
// 896 blocks x (n, 8 rows): contiguous 1792B reads per channel, 28 independent
// float4 loads/thread. LDS transpose tile is packed-u32 c-major: writes are
// lane-consecutive words (conflict-free), reads are 4-lane word broadcasts.
__global__ __launch_bounds__(256) void k_quant(const float* __restrict__ x,
                                               const unsigned* __restrict__ maxbits,
                                               int8_t* __restrict__ k8) {
    __shared__ unsigned tword[64 * 112];   // [c][u]  (u = packed float4 index in 8-row chunk)
    const int n  = blockIdx.x / 7;
    const int y8 = (blockIdx.x % 7) * 8;
    const float T = fminf(fmaxf(__uint_as_float(*maxbits), 1e-10f), 255.0f);
    const float* xb = x + (size_t)n * 64 * HW_ + y8 * 56;
#pragma unroll
    for (int it = 0; it < 28; it++) {
        const int flat = it * 256 + threadIdx.x;       // < 7168
        const int c = flat / 112, u = flat - c * 112;
        float4 v = *(const float4*)(xb + (size_t)c * HW_ + u * 4);
        float vv[4] = {v.x, v.y, v.z, v.w};
        unsigned pack = 0;
#pragma unroll
        for (int q = 0; q < 4; q++) {
            float t = fminf(fmaxf(vv[q], -T), T);
            float uq = __fdiv_rn(t, T);
            int k = (int)rintf(__fmul_rn(uq, 7.0f));
            pack |= ((unsigned)k & 0xFFu) << (8 * q);
        }
        tword[c * 112 + u] = pack;
    }
    __syncthreads();
#pragma unroll
    for (int it = 0; it < 7; it++) {
        const int w = it * 256 + threadIdx.x;          // < 1792
        const int rg = w / 56, xx = w - rg * 56;
        const int r = rg >> 2, g = rg & 3;
        const int sh = (xx & 3) * 8;
        const int ub = r * 14 + (xx >> 2);
        unsigned b[4];
#pragma unroll
        for (int q = 0; q < 4; q++) {
            unsigned acc = 0;
#pragma unroll
            for (int c2 = 0; c2 < 4; c2++) {
                unsigned byte = (tword[(g * 16 + q * 4 + c2) * 112 + ub] >> sh) & 0xFFu;
                acc |= byte << (8 * c2);
            }
            b[q] = acc;
        }
        int4 outv; outv.x = (int)b[0]; outv.y = (int)b[1]; outv.z = (int)b[2]; outv.w = (int)b[3];
        *(int4*)(k8 + ((((size_t)(n * 56 + y8 + r)) * 4 + g) * 56 + xx) * 16) = outv;
    }
}

// --------------------------- weight binarization, numpy-pairwise-faithful f32
__device__ __forceinline__ float pw_reduce64(float r) {
    r = __fadd_rn(r, __shfl_xor(r, 1, 64));
    r = __fadd_rn(r, __shfl_xor(r, 2, 64));
    r = __fadd_rn(r, __shfl_xor(r, 4, 64));
    r = __fadd_rn(r, __shfl_xor(r, 8, 64));
    r = __fadd_rn(r, __shfl_xor(r, 16, 64));
    r = __fadd_rn(r, __shfl_xor(r, 32, 64));
    return r;
}

__global__ void k_prepw(const float* __restrict__ w1, const float* __restrict__ w2,
                        int8_t* __restrict__ wb, float* __restrict__ par) {
    const int layer = blockIdx.x >> 6;
    const int co    = blockIdx.x & 63;
    const float* w = (layer ? w2 : w1) + (size_t)co * 576;
    const int lane = threadIdx.x;
    const int base = (lane >> 3) * 72 + (lane & 7);

    float v[9];
#pragma unroll
    for (int i = 0; i < 9; i++) v[i] = w[base + 8 * i];

    float s = v[0];
#pragma unroll
    for (int i = 1; i < 9; i++) s = __fadd_rn(s, v[i]);
    const float mean = __fdiv_rn(pw_reduce64(s), 576.0f);

    float d0 = __fsub_rn(v[0], mean);
    float sq = __fmul_rn(d0, d0);
#pragma unroll
    for (int i = 1; i < 9; i++) {
        float d = __fsub_rn(v[i], mean);
        sq = __fadd_rn(sq, __fmul_rn(d, d));
    }
    const float sig = __fsqrt_rn(__fdiv_rn(pw_reduce64(sq), 575.0f));

    float sa = fabsf(__fdiv_rn(__fsub_rn(v[0], mean), sig));
#pragma unroll
    for (int i = 1; i < 9; i++)
        sa = __fadd_rn(sa, fabsf(__fdiv_rn(__fsub_rn(v[i], mean), sig)));
    const float ma = __fdiv_rn(pw_reduce64(sa), 576.0f);
    const float p  = rintf(log2f(ma));
    if (lane == 0) par[256 + layer * 64 + co] = __fdiv_rn(exp2f(p), 7.0f);  // scf = 2^p/7

#pragma unroll
    for (int i = 0; i < 9; i++) {
        int ig = base + 8 * i;
        float d = __fsub_rn(v[i], mean);
        int8_t sg = (d > 0.0f) ? (int8_t)1 : ((d < 0.0f) ? (int8_t)-1 : (int8_t)0);
        int ci = ig / 9, t = ig % 9;
        wb[((((size_t)layer * 4 + (ci >> 4)) * 9 + t) * 64 + co) * 16 + (ci & 15)] = sg;
    }
}

// -------------------------------- BN folded affine, quantized, faithful f32
__global__ void k_prepbn(const float* g1, const float* bb1, const float* mm1, const float* vv1,
                         const float* g2, const float* bb2, const float* mm2, const float* vv2,
                         float* __restrict__ par) {
    const int layer = threadIdx.x >> 6;
    const int c = threadIdx.x & 63;
    const float* g  = layer ? g2  : g1;
    const float* be = layer ? bb2 : bb1;
    const float* mu = layer ? mm2 : mm1;
    const float* va = layer ? vv2 : vv1;
    const float stdv = __fsqrt_rn(__fadd_rn(va[c], 1e-5f));
    const float w = __fdiv_rn(g[c], stdv);
    const float b = __fsub_rn(be[c], __fmul_rn(w, mu[c]));
    float aw = fabsf(w), ab = fabsf(b);
    for (int off = 32; off; off >>= 1) {
        aw = fmaxf(aw, __shfl_xor(aw, off, 64));
        ab = fmaxf(ab, __shfl_xor(ab, off, 64));
    }
    const float Tw = fminf(fmaxf(aw, 1e-10f), 255.0f);
    const float Tb = fminf(fmaxf(ab, 1e-10f), 255.0f);
    {
        float vq = __fdiv_rn(fminf(fmaxf(w, -Tw), Tw), Tw);
        float r  = rintf(__fmul_rn(vq, 7.0f));
        float qf = __fadd_rn(vq, __fsub_rn(__fdiv_rn(r, 7.0f), vq));
        par[layer * 64 + c] = __fmul_rn(qf, Tw);
    }
    {
        float vq = __fdiv_rn(fminf(fmaxf(b, -Tb), Tb), Tb);
        float r  = rintf(__fmul_rn(vq, 4095.0f));
        float qf = __fadd_rn(vq, __fsub_rn(__fdiv_rn(r, 4095.0f), vq));
        par[128 + layer * 64 + c] = __fmul_rn(qf, Tb);
    }
}

// ------------------------------------------------ fused conv + BN + residual
// grid: B*28 blocks (n, 2 rows) -> M=112, N=64; 4 waves, one 32-M-tile each.
// LDS 51840 B (3 blocks/CU), conflict-free b128 reads. One barrier total.
// Epilogue: pure f32 arithmetic (R2/R3 bitwise-proven chain) - NO global LUTs.
// conv1: mfma(x,w) -> C col=co (int8 g-split direct store)
// conv2: mfma(w,x) -> C col=m  (coalesced f32 NCHW direct store)
template <int LAYER>
__global__ __launch_bounds__(256) void k_conv(const int8_t* __restrict__ kin,
                                              const int8_t* __restrict__ wb,
                                              const float* __restrict__ par,
                                              int8_t* __restrict__ kout,
                                              float* __restrict__ fout) {
    __shared__ __align__(16) int8_t halo[4 * 4 * 58 * 16];   // 14848 B
    __shared__ __align__(16) int8_t wsm[4 * 9 * 64 * 16];    // 36864 B
    __shared__ float xqlut[16];
    const int n  = blockIdx.x / 28;
    const int y0 = (blockIdx.x % 28) * 2;
    const int tid = threadIdx.x;

    for (int u = tid; u < 928; u += 256) {            // halo: g4 x r4 x x58
        int xx = u % 58, gr = u / 58;
        int g = gr >> 2, r = gr & 3;
        int y = y0 - 1 + r, xg = xx - 1;
        int4 val = {0, 0, 0, 0};
        if ((unsigned)y < 56u && (unsigned)xg < 56u)
            val = *(const int4*)(kin + ((((size_t)(n * 56 + y)) * 4 + g) * 56 + xg) * 16);
        *(int4*)(halo + ((g * 4 + r) * 58 + xx) * 16) = val;
    }
    const int8_t* wsrc = wb + (size_t)(LAYER - 1) * 36864;
    for (int u = tid; u < 2304; u += 256)
        *(int4*)(wsm + u * 16) = *(const int4*)(wsrc + u * 16);
    if (tid < 15) xqlut[tid] = __fdiv_rn((float)(tid - 7), 7.0f);
    __syncthreads();

    const int wv = tid >> 6, lane = tid & 63;
    const int ml = lane & 31, khalf = lane >> 5;
    const int mbase = wv * 32;

    const int m = mbase + ml;
    const int m_eff = (m < 112) ? m : 111;
    const int rm = m_eff / 56, cm = m_eff % 56;

    v16i acc0, acc1;
#pragma unroll
    for (int i = 0; i < 16; i++) { acc0[i] = 0; acc1[i] = 0; }

#pragma unroll
    for (int s = 0; s < 9; s++) {
        const int ky = s / 3, kx = s % 3;
#pragma unroll
        for (int kb = 0; kb < 2; kb++) {
            const int g = kb * 2 + khalf;
            v4i a  = *(const v4i*)(halo + ((g * 4 + rm + ky) * 58 + cm + kx) * 16);
            v4i b0 = *(const v4i*)(wsm + ((g * 9 + s) * 64 + ml) * 16);
            v4i b1 = *(const v4i*)(wsm + ((g * 9 + s) * 64 + ml + 32) * 16);
            if (LAYER == 1) {
                acc0 = __builtin_amdgcn_mfma_i32_32x32x32_i8(a, b0, acc0, 0, 0, 0);
                acc1 = __builtin_amdgcn_mfma_i32_32x32x32_i8(a, b1, acc1, 0, 0, 0);
            } else {
                acc0 = __builtin_amdgcn_mfma_i32_32x32x32_i8(b0, a, acc0, 0, 0, 0);
                acc1 = __builtin_amdgcn_mfma_i32_32x32x32_i8(b1, a, acc1, 0, 0, 0);
            }
        }
    }

    const float* qw = par + (LAYER - 1) * 64;
    const float* qb = par + 128 + (LAYER - 1) * 64;
    const float* sc = par + 256 + (LAYER - 1) * 64;

    if (LAYER == 1) {
        // C: col(lane)=co=ml+32t, row=mrow
#pragma unroll
        for (int t = 0; t < 2; t++) {
            const int co = ml + 32 * t;
            const float qwf = qw[co], qbf = qb[co], scf = sc[co];
#pragma unroll
            for (int r = 0; r < 16; r++) {
                const int mrow = mbase + 4 * khalf + (r & 3) + 8 * (r >> 2);
                if (mrow >= 112) continue;
                const float Sf = (float)(t ? acc1[r] : acc0[r]);    // exact integer
                float convf = __fmul_rn(Sf, scf);                   // = S * 2^p / 7
                float xb = __fdiv_rn(convf, 576.0f);
                float rr = rintf(__fmul_rn(xb, 1023.0f));
                float q1 = __fdiv_rn(rr, 1023.0f);
                float y1 = __fadd_rn(xb, __fsub_rn(q1, xb));
                float aq = __fmul_rn(y1, 576.0f);
                const int rloc = mrow / 56, cloc = mrow % 56;
                const int kc = (int)halo[(((co >> 4) * 4 + rloc + 1) * 58 + cloc + 1) * 16 + (co & 15)];
                const float xq = xqlut[kc + 7];
                float val = __fadd_rn(__fadd_rn(__fmul_rn(aq, qwf), qbf), xq);
                val = fminf(fmaxf(val, -1.0f), 1.0f);
                const int k2 = (int)rintf(__fmul_rn(val, 7.0f));    // T1 == 1.0
                kout[((((size_t)(n * 56 + y0 + rloc)) * 4 + (co >> 4)) * 56 + cloc) * 16 + (co & 15)]
                    = (int8_t)k2;
            }
        }
    } else {
        // C: col(lane)=m, row=co=(r&3)+8*(r>>2)+4*khalf+32t
        int kcw[16];
        {
            const int4* hp = (const int4*)halo;
#pragma unroll
            for (int g = 0; g < 4; g++) {
                int4 chunk = hp[(g * 4 + rm + 1) * 58 + cm + 1];
                kcw[g * 4 + 0] = chunk.x; kcw[g * 4 + 1] = chunk.y;
                kcw[g * 4 + 2] = chunk.z; kcw[g * 4 + 3] = chunk.w;
            }
        }
        float* fn = fout + (size_t)n * 64 * HW_ + (size_t)(y0 + rm) * 56 + cm;
        const bool mok = (m < 112);
#pragma unroll
        for (int t = 0; t < 2; t++) {
#pragma unroll
            for (int r = 0; r < 16; r++) {
                const int co = (r & 3) + 8 * (r >> 2) + 4 * khalf + 32 * t;
                const float qwf = qw[co], qbf = qb[co], scf = sc[co];
                const float Sf = (float)(t ? acc1[r] : acc0[r]);
                float convf = __fmul_rn(Sf, scf);
                float xb = __fdiv_rn(convf, 576.0f);
                float rr = rintf(__fmul_rn(xb, 1023.0f));
                float q1 = __fdiv_rn(rr, 1023.0f);
                float y1 = __fadd_rn(xb, __fsub_rn(q1, xb));
                float aq = __fmul_rn(y1, 576.0f);
                const int kc = (int)(int8_t)(kcw[co >> 2] >> ((co & 3) * 8));
                const float xq = xqlut[kc + 7];
                float val = __fadd_rn(__fadd_rn(__fmul_rn(aq, qwf), qbf), xq);
                val = fminf(fmaxf(val, -1.0f), 1.0f);
                if (mok) fn[(size_t)co * HW_] = val;
            }
        }
    }
}

// ----------------------------------------------------------------- launcher
extern "C" void kernel_launch(void* const* d_in, const int* in_sizes, int n_in,
                              void* d_out, int out_size, void* d_ws, size_t ws_size,
                              hipStream_t stream) {
    const float* x  = (const float*)d_in[0];
    const float* w1 = (const float*)d_in[1];
    const float* w2 = (const float*)d_in[2];
    const float* g1 = (const float*)d_in[3];
    const float* b1 = (const float*)d_in[4];
    const float* m1 = (const float*)d_in[5];
    const float* v1 = (const float*)d_in[6];
    const float* g2 = (const float*)d_in[7];
    const float* b2 = (const float*)d_in[8];
    const float* m2 = (const float*)d_in[9];
    const float* v2 = (const float*)d_in[10];

    char* ws = (char*)d_ws;
    int8_t*  k0  = (int8_t*)(ws + OFF_K0);
    int8_t*  k1  = (int8_t*)(ws + OFF_K1);
    int8_t*  wbp = (int8_t*)(ws + OFF_WB);
    float*   par = (float*)(ws + OFF_PAR);
    unsigned* mx = (unsigned*)(ws + OFF_MAX);

    hipMemsetAsync(mx, 0, 4, stream);
    k_absmax<<<2048, 256, 0, stream>>>(x, mx);
    k_quant<<<B_ * 7, 256, 0, stream>>>(x, mx, k0);
    k_prepw<<<128, 64, 0, stream>>>(w1, w2, wbp, par);
    k_prepbn<<<1, 128, 0, stream>>>(g1, b1, m1, v1, g2, b2, m2, v2, par);
    k_conv<1><<<B_ * 28, 256, 0, stream>>>(k0, wbp, par, k1, nullptr);
    k_conv<2><<<B_ * 28, 256, 0, stream>>>(k1, wbp, par, nullptr, (float*)d_out);
}